// Round 5
// baseline (32.893 us; speedup 1.0000x reference)
//
#include <hip/hip_runtime.h>
#include <math.h>

// ---------------------------------------------------------------------------
// HierarchicalCubeMap: mip pyramid build (2 kernels, RGBA-padded levels 1..9)
// + per-ray trilinear cubemap sampling (1 kernel, mips 5..9 staged in LDS,
//   4 rays/thread, float4 streaming I/O).
// Inputs (f32): viewdirs (B,3), saSample (B,1), bg_mat (6,512,512,3),
//               brightness (1), mul (1), mipbias (1)
// Output (f32): (B,3) = clip(exp(clip(brightness,-1,2) + mul*sample), .01, 1000)
// ---------------------------------------------------------------------------

#define BASE_R 512
#define N_MIPS 10  // log2(512)+1

// float offset of RGBA-padded mip level m (m>=1) in workspace:
// level k holds 6*4*(512>>k)^2 floats; off4(m) = 8*(4^9 - 4^(10-m))
__device__ __forceinline__ size_t mip_off4(int m) {
    return (size_t)8 * (262144u - (1u << (2 * (10 - m))));
}

// ---------------------------------------------------------------------------
// Fused pyramid: levels 1..5. Grid = 6 faces * 16*16 tiles of 32x32 texels.
// (unchanged from round 4 — byte-identical output)
// ---------------------------------------------------------------------------
__global__ __launch_bounds__(256) void pyramid_fused_kernel(
    const float* __restrict__ bg, float* __restrict__ ws) {
    __shared__ float bufA[32 * 32 * 3];  // 12288 B
    __shared__ float bufB[16 * 16 * 3];  //  3072 B

    const int tid = threadIdx.x;
    const int blk = blockIdx.x;
    const int tileX = blk & 15;
    const int tileY = (blk >> 4) & 15;
    const int f = blk >> 8;

    const size_t faceBase = (size_t)f * (512 * 512 * 3);
    for (int i = tid; i < 32 * 24; i += 256) {
        int row = i / 24;
        int col4 = i % 24;
        const float4 v = *reinterpret_cast<const float4*>(
            bg + faceBase + (size_t)(tileY * 32 + row) * 1536 + tileX * 96 + col4 * 4);
        *reinterpret_cast<float4*>(&bufA[row * 96 + col4 * 4]) = v;
    }
    __syncthreads();

    float* src = bufA;
    float* dst = bufB;
    int rs = 32;
#pragma unroll
    for (int L = 1; L <= 5; ++L) {
        const int rd = rs >> 1;
        const int r = BASE_R >> L;
        float4* gl4 = reinterpret_cast<float4*>(ws + mip_off4(L)) + (size_t)f * r * r;
        const int y0 = tileY * rd;
        const int x0 = tileX * rd;
        const int n = rd * rd;
        for (int i = tid; i < n; i += 256) {
            int x = i % rd;
            int y = i / rd;
            const float* p0 = src + ((2 * y) * rs + 2 * x) * 3;
            const float* p1 = p0 + rs * 3;
            float m0 = (p0[0] + p0[3] + p1[0] + p1[3]) * 0.25f;
            float m1 = (p0[1] + p0[4] + p1[1] + p1[4]) * 0.25f;
            float m2 = (p0[2] + p0[5] + p1[2] + p1[5]) * 0.25f;
            dst[i * 3 + 0] = m0;
            dst[i * 3 + 1] = m1;
            dst[i * 3 + 2] = m2;
            gl4[(size_t)(y0 + y) * r + (x0 + x)] = make_float4(m0, m1, m2, 0.0f);
        }
        __syncthreads();
        float* tmp = src; src = dst; dst = tmp;
        rs = rd;
    }
}

// ---------------------------------------------------------------------------
// Tail: levels 6..9 from level 5 (unchanged from round 4)
// ---------------------------------------------------------------------------
__global__ __launch_bounds__(256) void pyramid_tail_kernel(float* __restrict__ ws) {
    __shared__ float l5[4608];
    __shared__ float l6[1152];
    __shared__ float l7[288];
    __shared__ float l8[72];
    const int tid = threadIdx.x;

    const float4* g5 = reinterpret_cast<const float4*>(ws + mip_off4(5));
    for (int i = tid; i < 1536; i += 256) {
        float4 v = g5[i];
        l5[i * 3 + 0] = v.x; l5[i * 3 + 1] = v.y; l5[i * 3 + 2] = v.z;
    }
    __syncthreads();

    float4* g6 = reinterpret_cast<float4*>(ws + mip_off4(6));
    for (int i = tid; i < 384; i += 256) {
        int x = i & 7, y = (i >> 3) & 7, f = i >> 6;
        const float* p0 = l5 + ((f * 16 + 2 * y) * 16 + 2 * x) * 3;
        const float* p1 = p0 + 48;
        float m0 = (p0[0] + p0[3] + p1[0] + p1[3]) * 0.25f;
        float m1 = (p0[1] + p0[4] + p1[1] + p1[4]) * 0.25f;
        float m2 = (p0[2] + p0[5] + p1[2] + p1[5]) * 0.25f;
        l6[i * 3 + 0] = m0; l6[i * 3 + 1] = m1; l6[i * 3 + 2] = m2;
        g6[i] = make_float4(m0, m1, m2, 0.0f);
    }
    __syncthreads();

    float4* g7 = reinterpret_cast<float4*>(ws + mip_off4(7));
    for (int i = tid; i < 96; i += 256) {
        int x = i & 3, y = (i >> 2) & 3, f = i >> 4;
        const float* p0 = l6 + ((f * 8 + 2 * y) * 8 + 2 * x) * 3;
        const float* p1 = p0 + 24;
        float m0 = (p0[0] + p0[3] + p1[0] + p1[3]) * 0.25f;
        float m1 = (p0[1] + p0[4] + p1[1] + p1[4]) * 0.25f;
        float m2 = (p0[2] + p0[5] + p1[2] + p1[5]) * 0.25f;
        l7[i * 3 + 0] = m0; l7[i * 3 + 1] = m1; l7[i * 3 + 2] = m2;
        g7[i] = make_float4(m0, m1, m2, 0.0f);
    }
    __syncthreads();

    float4* g8 = reinterpret_cast<float4*>(ws + mip_off4(8));
    for (int i = tid; i < 24; i += 256) {
        int x = i & 1, y = (i >> 1) & 1, f = i >> 2;
        const float* p0 = l7 + ((f * 4 + 2 * y) * 4 + 2 * x) * 3;
        const float* p1 = p0 + 12;
        float m0 = (p0[0] + p0[3] + p1[0] + p1[3]) * 0.25f;
        float m1 = (p0[1] + p0[4] + p1[1] + p1[4]) * 0.25f;
        float m2 = (p0[2] + p0[5] + p1[2] + p1[5]) * 0.25f;
        l8[i * 3 + 0] = m0; l8[i * 3 + 1] = m1; l8[i * 3 + 2] = m2;
        g8[i] = make_float4(m0, m1, m2, 0.0f);
    }
    __syncthreads();

    float4* g9 = reinterpret_cast<float4*>(ws + mip_off4(9));
    for (int i = tid; i < 6; i += 256) {
        const float* p = l8 + i * 12;
        float m0 = (p[0] + p[3] + p[6] + p[9]) * 0.25f;
        float m1 = (p[1] + p[4] + p[7] + p[10]) * 0.25f;
        float m2 = (p[2] + p[5] + p[8] + p[11]) * 0.25f;
        g9[i] = make_float4(m0, m1, m2, 0.0f);
    }
}

// ---------------------------------------------------------------------------
// Sampler
// ---------------------------------------------------------------------------
#define LDS_T_COUNT 2046  // float4s, levels 5..9 (1536+384+96+24+6)

// float4 offset of level L (5..9) inside the staged LDS region
__device__ __forceinline__ int lds_off4(int L) {
    return LDS_T_COUNT - 2 * ((1 << (2 * (10 - L))) - 1);
}

__device__ __forceinline__ float4 fetch_tex(const float4* __restrict__ wsT,
                                            const float4* __restrict__ ldsT,
                                            int L, int idx) {
    if (L >= 5) return ldsT[lds_off4(L) + idx];
    // float4 offset of level L (1..4) in ws = mip_off4(L)/4
    return wsT[2u * (262144u - (1u << (2 * (10 - L)))) + idx];
}

__device__ __forceinline__ void corner_idx(int Rm, int face, float s, float t,
                                           int& i00, int& i01, int& i10, int& i11,
                                           float& fu, float& fv) {
    float u = s * (float)Rm - 0.5f;
    float v = t * (float)Rm - 0.5f;
    float u0 = floorf(u);
    float v0 = floorf(v);
    fu = u - u0;
    fv = v - v0;
    int u0i = min(max((int)u0, 0), Rm - 1);
    int u1i = min(max((int)u0 + 1, 0), Rm - 1);
    int v0i = min(max((int)v0, 0), Rm - 1);
    int v1i = min(max((int)v0 + 1, 0), Rm - 1);
    int fb = face * Rm;
    i00 = (fb + v0i) * Rm + u0i;
    i01 = (fb + v0i) * Rm + u1i;
    i10 = (fb + v1i) * Rm + u0i;
    i11 = (fb + v1i) * Rm + u1i;
}

__device__ __forceinline__ void blend4(float4 c00, float4 c01, float4 c10, float4 c11,
                                       float fu, float fv, float o[3]) {
    o[0] = (c00.x * (1.0f - fu) + c01.x * fu) * (1.0f - fv) +
           (c10.x * (1.0f - fu) + c11.x * fu) * fv;
    o[1] = (c00.y * (1.0f - fu) + c01.y * fu) * (1.0f - fv) +
           (c10.y * (1.0f - fu) + c11.y * fu) * fv;
    o[2] = (c00.z * (1.0f - fu) + c01.z * fu) * (1.0f - fv) +
           (c10.z * (1.0f - fu) + c11.z * fu) * fv;
}

// 3-stride fallback for mip 0 (bg_mat) — essentially never taken but required.
__device__ __noinline__ void sample_bg(const float* __restrict__ bg, int face,
                                       float s, float t, float o[3]) {
    int i00, i01, i10, i11;
    float fu, fv;
    corner_idx(BASE_R, face, s, t, i00, i01, i10, i11, fu, fv);
    const float* p00 = bg + (size_t)i00 * 3;
    const float* p01 = bg + (size_t)i01 * 3;
    const float* p10 = bg + (size_t)i10 * 3;
    const float* p11 = bg + (size_t)i11 * 3;
#pragma unroll
    for (int c = 0; c < 3; ++c) {
        float top = p00[c] * (1.0f - fu) + p01[c] * fu;
        float bot = p10[c] * (1.0f - fu) + p11[c] * fu;
        o[c] = top * (1.0f - fv) + bot * fv;
    }
}

__device__ __forceinline__ void shade_ray(float x, float y, float z, float sav,
                                          const float* __restrict__ bg,
                                          const float4* __restrict__ wsT,
                                          const float4* __restrict__ ldsT,
                                          float bb, float mulv, float bias,
                                          float o[3]) {
    float ax = fabsf(x), ay = fabsf(y), az = fabsf(z);
    float ma = fmaxf(ax, fmaxf(ay, az));

    int face;
    float sc, tc;
    if (ax >= ay && ax >= az) {
        face = (x > 0.0f) ? 0 : 1;
        sc = (x > 0.0f) ? -z : z;
        tc = -y;
    } else if (ay >= az) {
        face = (y > 0.0f) ? 2 : 3;
        sc = x;
        tc = (y > 0.0f) ? z : -z;
    } else {
        face = (z > 0.0f) ? 4 : 5;
        sc = (z > 0.0f) ? x : -x;
        tc = -y;
    }
    float s = 0.5f * (sc / ma + 1.0f);
    float t = 0.5f * (tc / ma + 1.0f);

    // mip = (sa - log(saTexel))/log(4)/2 + bias, saTexel = 1/(ma*512*512).
    // Algebraic rewrite (EPS clip never binds: ma in [0.577, 1]):
    //   mip = sa/(2 ln4) + 0.25*log2(ma) + 18/4 + bias
    float mip = sav * 0.36067376022224085f + 0.25f * __log2f(ma) + 4.5f + bias;
    mip = fminf(fmaxf(mip, 0.0f), (float)(N_MIPS - 1));

    int m0 = (int)floorf(mip);
    int m1 = min(m0 + 1, N_MIPS - 1);
    float frac = mip - (float)m0;

    float lo[3], hi[3];
    if (m0 >= 1) {
        int Ra = BASE_R >> m0;
        int a00, a01, a10, a11;
        float afu, afv;
        corner_idx(Ra, face, s, t, a00, a01, a10, a11, afu, afv);
        float4 A00 = fetch_tex(wsT, ldsT, m0, a00);
        float4 A01 = fetch_tex(wsT, ldsT, m0, a01);
        float4 A10 = fetch_tex(wsT, ldsT, m0, a10);
        float4 A11 = fetch_tex(wsT, ldsT, m0, a11);
        blend4(A00, A01, A10, A11, afu, afv, lo);
    } else {
        sample_bg(bg, face, s, t, lo);
    }
    {
        int Rb = BASE_R >> m1;  // m1 >= 1 always
        int b00, b01, b10, b11;
        float bfu, bfv;
        corner_idx(Rb, face, s, t, b00, b01, b10, b11, bfu, bfv);
        float4 B00 = fetch_tex(wsT, ldsT, m1, b00);
        float4 B01 = fetch_tex(wsT, ldsT, m1, b01);
        float4 B10 = fetch_tex(wsT, ldsT, m1, b10);
        float4 B11 = fetch_tex(wsT, ldsT, m1, b11);
        blend4(B00, B01, B10, B11, bfu, bfv, hi);
    }

#pragma unroll
    for (int c = 0; c < 3; ++c) {
        float xv = bb + mulv * (lo[c] * (1.0f - frac) + hi[c] * frac);
        float e = __expf(xv);
        o[c] = fminf(fmaxf(e, 0.01f), 1000.0f);
    }
}

__global__ __launch_bounds__(256) void cubemap_sample_kernel(
    const float* __restrict__ vd, const float* __restrict__ sa,
    const float* __restrict__ bg, const float* __restrict__ ws,
    float* __restrict__ out, int B,
    const float* __restrict__ p_brightness,
    const float* __restrict__ p_mul,
    const float* __restrict__ p_mipbias) {
    __shared__ float4 ldsT[LDS_T_COUNT];  // mips 5..9, 32736 B

    // Stage: levels 5..9 are contiguous in ws starting at mip_off4(5).
    const float4* srcT = reinterpret_cast<const float4*>(ws + mip_off4(5));
    for (int i = threadIdx.x; i < LDS_T_COUNT; i += 256) ldsT[i] = srcT[i];
    __syncthreads();

    const float4* wsT = reinterpret_cast<const float4*>(ws);
    const float bb = fminf(fmaxf(p_brightness[0], -1.0f), 2.0f);
    const float mulv = p_mul[0];
    const float bias = p_mipbias[0];

    int gid = blockIdx.x * 256 + threadIdx.x;
    int base = gid * 4;
    if (base + 3 < B) {
        // Fast path: 4 rays, fully vectorized I/O.
        const float4* vd4 = reinterpret_cast<const float4*>(vd);
        const float4* sa4 = reinterpret_cast<const float4*>(sa);
        float4* out4 = reinterpret_cast<float4*>(out);
        float4 a = vd4[3 * (size_t)gid + 0];
        float4 b = vd4[3 * (size_t)gid + 1];
        float4 c = vd4[3 * (size_t)gid + 2];
        float4 s4 = sa4[gid];
        float res[12];
        shade_ray(a.x, a.y, a.z, s4.x, bg, wsT, ldsT, bb, mulv, bias, &res[0]);
        shade_ray(a.w, b.x, b.y, s4.y, bg, wsT, ldsT, bb, mulv, bias, &res[3]);
        shade_ray(b.z, b.w, c.x, s4.z, bg, wsT, ldsT, bb, mulv, bias, &res[6]);
        shade_ray(c.y, c.z, c.w, s4.w, bg, wsT, ldsT, bb, mulv, bias, &res[9]);
        out4[3 * (size_t)gid + 0] = make_float4(res[0], res[1], res[2], res[3]);
        out4[3 * (size_t)gid + 1] = make_float4(res[4], res[5], res[6], res[7]);
        out4[3 * (size_t)gid + 2] = make_float4(res[8], res[9], res[10], res[11]);
    } else {
        for (int r = base; r < B; ++r) {
            float o[3];
            shade_ray(vd[3 * r + 0], vd[3 * r + 1], vd[3 * r + 2], sa[r],
                      bg, wsT, ldsT, bb, mulv, bias, o);
            out[3 * r + 0] = o[0];
            out[3 * r + 1] = o[1];
            out[3 * r + 2] = o[2];
        }
    }
}

extern "C" void kernel_launch(void* const* d_in, const int* in_sizes, int n_in,
                              void* d_out, int out_size, void* d_ws, size_t ws_size,
                              hipStream_t stream) {
    const float* viewdirs = (const float*)d_in[0];
    const float* saSample = (const float*)d_in[1];
    const float* bg_mat = (const float*)d_in[2];
    const float* brightness = (const float*)d_in[3];
    const float* mul = (const float*)d_in[4];
    const float* mipbias = (const float*)d_in[5];
    float* out = (float*)d_out;
    float* ws = (float*)d_ws;

    int B = in_sizes[1];  // saSample has B elements

    pyramid_fused_kernel<<<6 * 16 * 16, 256, 0, stream>>>(bg_mat, ws);
    pyramid_tail_kernel<<<1, 256, 0, stream>>>(ws);

    int blocks = (B + 1023) / 1024;  // 4 rays/thread, 256 threads/block
    cubemap_sample_kernel<<<blocks, 256, 0, stream>>>(
        viewdirs, saSample, bg_mat, ws, out, B, brightness, mul, mipbias);
}

// Round 6
// 30.923 us; speedup vs baseline: 1.0637x; 1.0637x over previous
//
#include <hip/hip_runtime.h>
#include <math.h>

// ---------------------------------------------------------------------------
// HierarchicalCubeMap, 2-kernel structure:
//   K1 pyramid_fused_kernel: bg -> RGBA-padded mips 1..5 in ws.
//   K2 cubemap_sample_kernel: stages mip 5 to LDS, computes mips 6..9 in LDS
//      (bit-identical averaging), then shades 4 rays/thread.
// Inputs (f32): viewdirs (B,3), saSample (B,1), bg_mat (6,512,512,3),
//               brightness (1), mul (1), mipbias (1)
// Output (f32): (B,3) = clip(exp(clip(brightness,-1,2) + mul*sample), .01, 1000)
// ---------------------------------------------------------------------------

#define BASE_R 512
#define N_MIPS 10  // log2(512)+1

// float offset of RGBA-padded mip level m (m>=1) in workspace:
// level k holds 6*4*(512>>k)^2 floats; off4(m) = 8*(4^9 - 4^(10-m))
__device__ __forceinline__ size_t mip_off4(int m) {
    return (size_t)8 * (262144u - (1u << (2 * (10 - m))));
}

// ---------------------------------------------------------------------------
// Fused pyramid: levels 1..5. Grid = 6 faces * 16*16 tiles of 32x32 texels.
// (byte-identical to rounds 4/5)
// ---------------------------------------------------------------------------
__global__ __launch_bounds__(256) void pyramid_fused_kernel(
    const float* __restrict__ bg, float* __restrict__ ws) {
    __shared__ float bufA[32 * 32 * 3];  // 12288 B
    __shared__ float bufB[16 * 16 * 3];  //  3072 B

    const int tid = threadIdx.x;
    const int blk = blockIdx.x;
    const int tileX = blk & 15;
    const int tileY = (blk >> 4) & 15;
    const int f = blk >> 8;

    const size_t faceBase = (size_t)f * (512 * 512 * 3);
    for (int i = tid; i < 32 * 24; i += 256) {
        int row = i / 24;
        int col4 = i % 24;
        const float4 v = *reinterpret_cast<const float4*>(
            bg + faceBase + (size_t)(tileY * 32 + row) * 1536 + tileX * 96 + col4 * 4);
        *reinterpret_cast<float4*>(&bufA[row * 96 + col4 * 4]) = v;
    }
    __syncthreads();

    float* src = bufA;
    float* dst = bufB;
    int rs = 32;
#pragma unroll
    for (int L = 1; L <= 5; ++L) {
        const int rd = rs >> 1;
        const int r = BASE_R >> L;
        float4* gl4 = reinterpret_cast<float4*>(ws + mip_off4(L)) + (size_t)f * r * r;
        const int y0 = tileY * rd;
        const int x0 = tileX * rd;
        const int n = rd * rd;
        for (int i = tid; i < n; i += 256) {
            int x = i % rd;
            int y = i / rd;
            const float* p0 = src + ((2 * y) * rs + 2 * x) * 3;
            const float* p1 = p0 + rs * 3;
            float m0 = (p0[0] + p0[3] + p1[0] + p1[3]) * 0.25f;
            float m1 = (p0[1] + p0[4] + p1[1] + p1[4]) * 0.25f;
            float m2 = (p0[2] + p0[5] + p1[2] + p1[5]) * 0.25f;
            dst[i * 3 + 0] = m0;
            dst[i * 3 + 1] = m1;
            dst[i * 3 + 2] = m2;
            gl4[(size_t)(y0 + y) * r + (x0 + x)] = make_float4(m0, m1, m2, 0.0f);
        }
        __syncthreads();
        float* tmp = src; src = dst; dst = tmp;
        rs = rd;
    }
}

// ---------------------------------------------------------------------------
// Sampler: LDS holds mips 5..9 as float4 (2046 entries, 32736 B).
// Layout: L5 @ 0 (1536), L6 @ 1536 (384), L7 @ 1920 (96), L8 @ 2016 (24),
//         L9 @ 2040 (6).   lds_off4(L) = 2046 - 2*(4^(10-L) - 1).
// ---------------------------------------------------------------------------
#define LDS_T_COUNT 2046

__device__ __forceinline__ int lds_off4(int L) {
    return LDS_T_COUNT - 2 * ((1 << (2 * (10 - L))) - 1);
}

__device__ __forceinline__ float4 f4avg(float4 a, float4 b, float4 c, float4 d) {
    // Same association as reference chain: ((a+b)+c)+d then *0.25
    return make_float4((a.x + b.x + c.x + d.x) * 0.25f,
                       (a.y + b.y + c.y + d.y) * 0.25f,
                       (a.z + b.z + c.z + d.z) * 0.25f, 0.0f);
}

__device__ __forceinline__ float4 fetch_tex(const float4* __restrict__ wsT,
                                            const float4* __restrict__ ldsT,
                                            int L, int idx) {
    if (L >= 5) return ldsT[lds_off4(L) + idx];
    return wsT[2u * (262144u - (1u << (2 * (10 - L)))) + idx];
}

__device__ __forceinline__ void corner_idx(int Rm, int face, float s, float t,
                                           int& i00, int& i01, int& i10, int& i11,
                                           float& fu, float& fv) {
    float u = s * (float)Rm - 0.5f;
    float v = t * (float)Rm - 0.5f;
    float u0 = floorf(u);
    float v0 = floorf(v);
    fu = u - u0;
    fv = v - v0;
    int u0i = min(max((int)u0, 0), Rm - 1);
    int u1i = min(max((int)u0 + 1, 0), Rm - 1);
    int v0i = min(max((int)v0, 0), Rm - 1);
    int v1i = min(max((int)v0 + 1, 0), Rm - 1);
    int fb = face * Rm;
    i00 = (fb + v0i) * Rm + u0i;
    i01 = (fb + v0i) * Rm + u1i;
    i10 = (fb + v1i) * Rm + u0i;
    i11 = (fb + v1i) * Rm + u1i;
}

__device__ __forceinline__ void blend4(float4 c00, float4 c01, float4 c10, float4 c11,
                                       float fu, float fv, float o[3]) {
    o[0] = (c00.x * (1.0f - fu) + c01.x * fu) * (1.0f - fv) +
           (c10.x * (1.0f - fu) + c11.x * fu) * fv;
    o[1] = (c00.y * (1.0f - fu) + c01.y * fu) * (1.0f - fv) +
           (c10.y * (1.0f - fu) + c11.y * fu) * fv;
    o[2] = (c00.z * (1.0f - fu) + c01.z * fu) * (1.0f - fv) +
           (c10.z * (1.0f - fu) + c11.z * fu) * fv;
}

// 3-stride fallback for mip 0 (bg_mat) — essentially never taken but required.
__device__ __noinline__ void sample_bg(const float* __restrict__ bg, int face,
                                       float s, float t, float o[3]) {
    int i00, i01, i10, i11;
    float fu, fv;
    corner_idx(BASE_R, face, s, t, i00, i01, i10, i11, fu, fv);
    const float* p00 = bg + (size_t)i00 * 3;
    const float* p01 = bg + (size_t)i01 * 3;
    const float* p10 = bg + (size_t)i10 * 3;
    const float* p11 = bg + (size_t)i11 * 3;
#pragma unroll
    for (int c = 0; c < 3; ++c) {
        float top = p00[c] * (1.0f - fu) + p01[c] * fu;
        float bot = p10[c] * (1.0f - fu) + p11[c] * fu;
        o[c] = top * (1.0f - fv) + bot * fv;
    }
}

__device__ __forceinline__ void shade_ray(float x, float y, float z, float sav,
                                          const float* __restrict__ bg,
                                          const float4* __restrict__ wsT,
                                          const float4* __restrict__ ldsT,
                                          float bb, float mulv, float bias,
                                          float o[3]) {
    float ax = fabsf(x), ay = fabsf(y), az = fabsf(z);
    float ma = fmaxf(ax, fmaxf(ay, az));

    int face;
    float sc, tc;
    if (ax >= ay && ax >= az) {
        face = (x > 0.0f) ? 0 : 1;
        sc = (x > 0.0f) ? -z : z;
        tc = -y;
    } else if (ay >= az) {
        face = (y > 0.0f) ? 2 : 3;
        sc = x;
        tc = (y > 0.0f) ? z : -z;
    } else {
        face = (z > 0.0f) ? 4 : 5;
        sc = (z > 0.0f) ? x : -x;
        tc = -y;
    }
    float s = 0.5f * (sc / ma + 1.0f);
    float t = 0.5f * (tc / ma + 1.0f);

    // mip = sa/(2 ln4) + 0.25*log2(ma) + 4.5 + bias  (EPS clip never binds)
    float mip = sav * 0.36067376022224085f + 0.25f * __log2f(ma) + 4.5f + bias;
    mip = fminf(fmaxf(mip, 0.0f), (float)(N_MIPS - 1));

    int m0 = (int)floorf(mip);
    int m1 = min(m0 + 1, N_MIPS - 1);
    float frac = mip - (float)m0;

    float lo[3], hi[3];
    if (m0 >= 1) {
        int Ra = BASE_R >> m0;
        int a00, a01, a10, a11;
        float afu, afv;
        corner_idx(Ra, face, s, t, a00, a01, a10, a11, afu, afv);
        float4 A00 = fetch_tex(wsT, ldsT, m0, a00);
        float4 A01 = fetch_tex(wsT, ldsT, m0, a01);
        float4 A10 = fetch_tex(wsT, ldsT, m0, a10);
        float4 A11 = fetch_tex(wsT, ldsT, m0, a11);
        blend4(A00, A01, A10, A11, afu, afv, lo);
    } else {
        sample_bg(bg, face, s, t, lo);
    }
    {
        int Rb = BASE_R >> m1;  // m1 >= 1 always
        int b00, b01, b10, b11;
        float bfu, bfv;
        corner_idx(Rb, face, s, t, b00, b01, b10, b11, bfu, bfv);
        float4 B00 = fetch_tex(wsT, ldsT, m1, b00);
        float4 B01 = fetch_tex(wsT, ldsT, m1, b01);
        float4 B10 = fetch_tex(wsT, ldsT, m1, b10);
        float4 B11 = fetch_tex(wsT, ldsT, m1, b11);
        blend4(B00, B01, B10, B11, bfu, bfv, hi);
    }

#pragma unroll
    for (int c = 0; c < 3; ++c) {
        float xv = bb + mulv * (lo[c] * (1.0f - frac) + hi[c] * frac);
        float e = __expf(xv);
        o[c] = fminf(fmaxf(e, 0.01f), 1000.0f);
    }
}

__global__ __launch_bounds__(256) void cubemap_sample_kernel(
    const float* __restrict__ vd, const float* __restrict__ sa,
    const float* __restrict__ bg, const float* __restrict__ ws,
    float* __restrict__ out, int B,
    const float* __restrict__ p_brightness,
    const float* __restrict__ p_mul,
    const float* __restrict__ p_mipbias) {
    __shared__ float4 ldsT[LDS_T_COUNT];  // mips 5..9, 32736 B
    const int tid = threadIdx.x;

    // Stage mip 5 from ws (written by pyramid kernel).
    const float4* srcT = reinterpret_cast<const float4*>(ws + mip_off4(5));
    for (int i = tid; i < 1536; i += 256) ldsT[i] = srcT[i];
    __syncthreads();

    // Compute mips 6..9 in LDS (bit-identical averaging order).
    for (int i = tid; i < 384; i += 256) {  // L6: 6*8*8
        int x = i & 7, y = (i >> 3) & 7, f = i >> 6;
        int b = (f * 16 + 2 * y) * 16 + 2 * x;
        ldsT[1536 + i] = f4avg(ldsT[b], ldsT[b + 1], ldsT[b + 16], ldsT[b + 17]);
    }
    __syncthreads();
    for (int i = tid; i < 96; i += 256) {   // L7: 6*4*4
        int x = i & 3, y = (i >> 2) & 3, f = i >> 4;
        int b = 1536 + (f * 8 + 2 * y) * 8 + 2 * x;
        ldsT[1920 + i] = f4avg(ldsT[b], ldsT[b + 1], ldsT[b + 8], ldsT[b + 9]);
    }
    __syncthreads();
    for (int i = tid; i < 24; i += 256) {   // L8: 6*2*2
        int x = i & 1, y = (i >> 1) & 1, f = i >> 2;
        int b = 1920 + (f * 4 + 2 * y) * 4 + 2 * x;
        ldsT[2016 + i] = f4avg(ldsT[b], ldsT[b + 1], ldsT[b + 4], ldsT[b + 5]);
    }
    __syncthreads();
    for (int i = tid; i < 6; i += 256) {    // L9: 6*1*1
        int b = 2016 + i * 4;
        ldsT[2040 + i] = f4avg(ldsT[b], ldsT[b + 1], ldsT[b + 2], ldsT[b + 3]);
    }
    __syncthreads();

    const float4* wsT = reinterpret_cast<const float4*>(ws);
    const float bb = fminf(fmaxf(p_brightness[0], -1.0f), 2.0f);
    const float mulv = p_mul[0];
    const float bias = p_mipbias[0];

    int gid = blockIdx.x * 256 + tid;
    int base = gid * 4;
    if (base + 3 < B) {
        const float4* vd4 = reinterpret_cast<const float4*>(vd);
        const float4* sa4 = reinterpret_cast<const float4*>(sa);
        float4* out4 = reinterpret_cast<float4*>(out);
        float4 a = vd4[3 * (size_t)gid + 0];
        float4 b = vd4[3 * (size_t)gid + 1];
        float4 c = vd4[3 * (size_t)gid + 2];
        float4 s4 = sa4[gid];
        float res[12];
        shade_ray(a.x, a.y, a.z, s4.x, bg, wsT, ldsT, bb, mulv, bias, &res[0]);
        shade_ray(a.w, b.x, b.y, s4.y, bg, wsT, ldsT, bb, mulv, bias, &res[3]);
        shade_ray(b.z, b.w, c.x, s4.z, bg, wsT, ldsT, bb, mulv, bias, &res[6]);
        shade_ray(c.y, c.z, c.w, s4.w, bg, wsT, ldsT, bb, mulv, bias, &res[9]);
        out4[3 * (size_t)gid + 0] = make_float4(res[0], res[1], res[2], res[3]);
        out4[3 * (size_t)gid + 1] = make_float4(res[4], res[5], res[6], res[7]);
        out4[3 * (size_t)gid + 2] = make_float4(res[8], res[9], res[10], res[11]);
    } else {
        for (int r = base; r < B; ++r) {
            float o[3];
            shade_ray(vd[3 * r + 0], vd[3 * r + 1], vd[3 * r + 2], sa[r],
                      bg, wsT, ldsT, bb, mulv, bias, o);
            out[3 * r + 0] = o[0];
            out[3 * r + 1] = o[1];
            out[3 * r + 2] = o[2];
        }
    }
}

extern "C" void kernel_launch(void* const* d_in, const int* in_sizes, int n_in,
                              void* d_out, int out_size, void* d_ws, size_t ws_size,
                              hipStream_t stream) {
    const float* viewdirs = (const float*)d_in[0];
    const float* saSample = (const float*)d_in[1];
    const float* bg_mat = (const float*)d_in[2];
    const float* brightness = (const float*)d_in[3];
    const float* mul = (const float*)d_in[4];
    const float* mipbias = (const float*)d_in[5];
    float* out = (float*)d_out;
    float* ws = (float*)d_ws;

    int B = in_sizes[1];  // saSample has B elements

    pyramid_fused_kernel<<<6 * 16 * 16, 256, 0, stream>>>(bg_mat, ws);

    int blocks = (B + 1023) / 1024;  // 4 rays/thread, 256 threads/block
    cubemap_sample_kernel<<<blocks, 256, 0, stream>>>(
        viewdirs, saSample, bg_mat, ws, out, B, brightness, mul, mipbias);
}